// Round 7
// baseline (381.857 us; speedup 1.0000x reference)
//
#include <hip/hip_runtime.h>

typedef __bf16 bf16;
typedef __bf16 bf16x2 __attribute__((ext_vector_type(2)));
typedef __bf16 bf16x8 __attribute__((ext_vector_type(8)));
typedef float  f32x4  __attribute__((ext_vector_type(4)));

#define MFMA16(a,b,c) __builtin_amdgcn_mfma_f32_16x16x32_bf16(a,b,c,0,0,0)
// async global->LDS DMA, 16B per lane; LDS dest is wave-uniform base + lane*16
#define GLL16(g, l) __builtin_amdgcn_global_load_lds( \
    (const __attribute__((address_space(1))) unsigned char*)(g), \
    (__attribute__((address_space(3))) unsigned char*)(l), 16, 0, 0)

constexpr int SEQ   = 2048;
constexpr int NH    = 16;
constexpr int HD    = 64;
constexpr int BATCH = 4;
constexpr int DM    = 1024;          // model dim
constexpr int ROWS  = BATCH * SEQ;   // 8192
constexpr size_t TEN = (size_t)BATCH * NH * SEQ * HD;   // 8,388,608 elems per tensor

// ---------------------------------------------------------------- prep: weight transpose (z=0..3) + x convert (z=4)
__global__ __launch_bounds__(256) void k_prep(const float* __restrict__ x,
                                              const float* __restrict__ W0,
                                              const float* __restrict__ W1,
                                              const float* __restrict__ W2,
                                              const float* __restrict__ W3,
                                              bf16* __restrict__ Wt_all,
                                              bf16* __restrict__ xb) {
    __shared__ float T[64][65];
    const int z = blockIdx.z;
    const int t = threadIdx.x;
    if (z == 4) {
        // convert x (fp32 -> bf16): 256 blocks x 256 threads x 128 elems
        const int bi = blockIdx.y * 16 + blockIdx.x;
#pragma unroll
        for (int c = 0; c < 16; c++) {
            const size_t idx = (size_t)c * 524288 + ((size_t)bi * 256 + t) * 8;
            float4 f0 = *(const float4*)(x + idx);
            float4 f1 = *(const float4*)(x + idx + 4);
            bf16x8 o;
            o[0] = (bf16)f0.x; o[1] = (bf16)f0.y; o[2] = (bf16)f0.z; o[3] = (bf16)f0.w;
            o[4] = (bf16)f1.x; o[5] = (bf16)f1.y; o[6] = (bf16)f1.z; o[7] = (bf16)f1.w;
            *(bf16x8*)(xb + idx) = o;
        }
        return;
    }
    const float* W = (z == 0) ? W0 : (z == 1) ? W1 : (z == 2) ? W2 : W3;
    bf16* Wt = Wt_all + (size_t)z * DM * DM;
    const int kb = blockIdx.x, nb = blockIdx.y;
    const int rl = t >> 2, seg = t & 3;
    const float* src = W + (size_t)(kb * 64 + rl) * DM + nb * 64 + seg * 16;
#pragma unroll
    for (int j4 = 0; j4 < 4; j4++) {
        float4 f = *(const float4*)(src + j4 * 4);
        T[rl][seg * 16 + j4 * 4 + 0] = f.x;
        T[rl][seg * 16 + j4 * 4 + 1] = f.y;
        T[rl][seg * 16 + j4 * 4 + 2] = f.z;
        T[rl][seg * 16 + j4 * 4 + 3] = f.w;
    }
    __syncthreads();
    bf16* dst = Wt + (size_t)(nb * 64 + rl) * DM + kb * 64 + seg * 16;
    bf16x8 o0, o1;
#pragma unroll
    for (int j = 0; j < 8; j++) {
        o0[j] = (bf16)T[seg * 16 + j][rl];
        o1[j] = (bf16)T[seg * 16 + 8 + j][rl];
    }
    *(bf16x8*)dst = o0;
    *(bf16x8*)(dst + 8) = o1;
}

// ---------------------------------------------------------------- GEMM (m97 structure)
// 128x128 tile, BK=32, global_load_lds(16B) staging, XOR-swizzled LDS.
// MODE 0: out bf16 scattered to [B,H,S,D] (+ z*TEN), with RoPE fused for z<2
//         (partner element via shfl_xor(1): col^1 lives in lane l16^1, same regs).
// MODE 1: out fp32 [row][col].
template <int MODE>
__global__ __launch_bounds__(256) void k_gemm(const bf16* __restrict__ A,
                                              const bf16* __restrict__ Wt0,
                                              const float* __restrict__ b0,
                                              const float* __restrict__ b1,
                                              const float* __restrict__ b2,
                                              void* __restrict__ out) {
    __shared__ __align__(1024) bf16 AsF[128 * 32];   // 8 KB, swizzled
    __shared__ __align__(1024) bf16 BsF[128 * 32];   // 8 KB, swizzled
    const int z = blockIdx.z;
    const bf16* Wt = Wt0 + (size_t)z * DM * DM;
    const float* bias = (z == 0) ? b0 : (z == 1) ? b1 : b2;

    const int t = threadIdx.x;
    const int w = t >> 6, lane = t & 63, quad = lane >> 4, l16 = lane & 15;
    const int bm = blockIdx.x * 128, bn = blockIdx.y * 128;   // x = M: A-sharers on one XCD
    const int wm = (w >> 1) * 64, wn = (w & 1) * 64;

    // staging: 8 chunks of 1024B per tile; wave w DMAs chunks w*2, w*2+1
    const int c0 = w * 2, c1 = w * 2 + 1;
    const int sg0 = c0 * 64 + lane, sg1 = c1 * 64 + lane;     // 16B segment idx 0..511
    const int r0 = sg0 >> 2, r1 = sg1 >> 2;                   // tile row 0..127
    const int csg0 = (sg0 & 3) ^ ((r0 >> 1) & 3);             // global segment (de-swizzled)
    const int csg1 = (sg1 & 3) ^ ((r1 >> 1) & 3);
    const bf16* gA0 = A  + (size_t)(bm + r0) * DM + csg0 * 8;
    const bf16* gA1 = A  + (size_t)(bm + r1) * DM + csg1 * 8;
    const bf16* gB0 = Wt + (size_t)(bn + r0) * DM + csg0 * 8;
    const bf16* gB1 = Wt + (size_t)(bn + r1) * DM + csg1 * 8;
    bf16* lA0 = AsF + c0 * 512;  // wave-uniform LDS chunk bases
    bf16* lA1 = AsF + c1 * 512;
    bf16* lB0 = BsF + c0 * 512;
    bf16* lB1 = BsF + c1 * 512;

    // fragment read pointers (loop-invariant; swizzled)
    const bf16* pA[4]; const bf16* pB[4];
#pragma unroll
    for (int mt = 0; mt < 4; mt++) {
        const int r = wm + mt * 16 + l16;
        pA[mt] = AsF + r * 32 + ((quad ^ ((r >> 1) & 3)) << 3);
    }
#pragma unroll
    for (int nt = 0; nt < 4; nt++) {
        const int r = wn + nt * 16 + l16;
        pB[nt] = BsF + r * 32 + ((quad ^ ((r >> 1) & 3)) << 3);
    }

    f32x4 zero = {0.f, 0.f, 0.f, 0.f};
    f32x4 acc[4][4];
#pragma unroll
    for (int mt = 0; mt < 4; mt++)
#pragma unroll
        for (int nt = 0; nt < 4; nt++) acc[mt][nt] = zero;

    for (int k0 = 0; k0 < DM; k0 += 32) {
        __syncthreads();               // waves done reading previous tile
        GLL16(gA0, lA0);
        GLL16(gA1, lA1);
        GLL16(gB0, lB0);
        GLL16(gB1, lB1);
        gA0 += 32; gA1 += 32; gB0 += 32; gB1 += 32;
        __syncthreads();               // vmcnt(0) drain: tile landed

        bf16x8 af[4], bfr[4];
#pragma unroll
        for (int mt = 0; mt < 4; mt++) af[mt]  = *(const bf16x8*)pA[mt];
#pragma unroll
        for (int nt = 0; nt < 4; nt++) bfr[nt] = *(const bf16x8*)pB[nt];
#pragma unroll
        for (int mt = 0; mt < 4; mt++)
#pragma unroll
            for (int nt = 0; nt < 4; nt++)
                acc[mt][nt] = MFMA16(af[mt], bfr[nt], acc[mt][nt]);
    }

    float bv[4], invf[4];
#pragma unroll
    for (int nt = 0; nt < 4; nt++) {
        const int col = bn + wn + nt * 16 + l16;
        bv[nt] = bias[col];
        if (MODE == 0) {
            // rope inv_freq for pair index i = (col%64)/2 : 10000^(-i/32)
            const int i = (col & 63) >> 1;
            invf[nt] = __builtin_exp2f(-0.41524101186092029f * (float)i);
        }
    }
    const int odd = l16 & 1;

#pragma unroll
    for (int mt = 0; mt < 4; mt++) {
#pragma unroll
        for (int nt = 0; nt < 4; nt++) {
            const int col = bn + wn + nt * 16 + l16;
#pragma unroll
            for (int rg = 0; rg < 4; rg++) {
                const int row = bm + wm + mt * 16 + quad * 4 + rg;
                float val = acc[mt][nt][rg] + bv[nt];
                if (MODE == 0) {
                    const int b = row >> 11, s = row & (SEQ - 1);
                    const int h = col >> 6, dd = col & 63;
                    if (z < 2) {   // fused RoPE on q,k (q also pre-scaled by 1/8)
                        const float partner = __shfl_xor(val, 1);
                        float sn, cs;
                        __sincosf((float)s * invf[nt], &sn, &cs);
                        val = odd ? (val * cs + partner * sn)
                                  : (val * cs - partner * sn);
                        if (z == 0) val *= 0.125f;
                    }
                    ((bf16*)out)[(size_t)z * TEN +
                                 (((size_t)(b * NH + h)) * SEQ + s) * HD + dd] = (bf16)val;
                } else {
                    ((float*)out)[(size_t)row * DM + col] = val;
                }
            }
        }
    }
}

// ---------------------------------------------------------------- V transpose: [B,H,S,D] -> [B,H,D,S]
__global__ __launch_bounds__(256) void k_vtrans(const bf16* __restrict__ v, bf16* __restrict__ vt) {
    __shared__ float T[64][65];
    const int t = threadIdx.x;
    const int sb = blockIdx.x, bh = blockIdx.y;
    const int rl = t >> 2, seg = t & 3;
    const bf16* src = v + ((size_t)bh * SEQ + sb * 64 + rl) * HD + seg * 16;
    bf16x8 i0 = *(const bf16x8*)src;
    bf16x8 i1 = *(const bf16x8*)(src + 8);
#pragma unroll
    for (int j = 0; j < 8; j++) {
        T[rl][seg * 16 + j]     = (float)i0[j];
        T[rl][seg * 16 + 8 + j] = (float)i1[j];
    }
    __syncthreads();
    bf16* dst = vt + ((size_t)bh * HD + rl) * SEQ + sb * 64 + seg * 16;
    bf16x8 o0, o1;
#pragma unroll
    for (int j = 0; j < 8; j++) {
        o0[j] = (bf16)T[seg * 16 + j][rl];
        o1[j] = (bf16)T[seg * 16 + 8 + j][rl];
    }
    *(bf16x8*)dst = o0;
    *(bf16x8*)(dst + 8) = o1;
}

// ---------------------------------------------------------------- flash attention (causal)
// grid: (bh=64, 16). qb = 15 - blockIdx.y (heavy-first). One 128-row q-block per block;
// 1024 blocks = 4/CU co-resident (launch_bounds(256,4)) so barrier drains hide behind
// other blocks (R6's 2-pass grid left only 2 blocks/CU -> 45% idle).
// Wave w owns rows w*32..w*32+31 (2 m-tiles). K/V/P in unpadded XOR-swizzled LDS
// (seg' = seg ^ (row&7)): fragment b128 reads 2-way = free; staging via global_load_lds.
// Softmax: fixed offset -10 in acc init; row-sum deferred to epilogue; P transpose via
// wave-private swizzled LDS (no barrier). Wave-level skip of fully-masked corner.
__global__ __launch_bounds__(256, 4) void k_attn(const bf16* __restrict__ q,
                                                 const bf16* __restrict__ k,
                                                 const bf16* __restrict__ vt,
                                                 bf16* __restrict__ y) {
    __shared__ __align__(1024) bf16 KsF[64 * 64];      // 8 KB [kv][d] swizzled
    __shared__ __align__(1024) bf16 VsF[64 * 64];      // 8 KB [d][kv] swizzled
    __shared__ __align__(1024) bf16 PsF[4 * 32 * 64];  // 16 KB per-wave P scratch, swizzled
    const int t = threadIdx.x;
    const int w = t >> 6, lane = t & 63, quad = lane >> 4, l16 = lane & 15;
    const int bh = blockIdx.x;                // bh fastest => y-blocks of one bh share an XCD
    const int qb = 15 - (int)blockIdx.y;      // heavy blocks dispatch first
    const int b = bh >> 4, h = bh & 15;

    // staging lane mapping: chunk = 8 rows x 64 elems (1 KB); lane -> (row, stored seg)
    const int srow = lane >> 3;                       // row within chunk
    const int gseg = (lane & 7) ^ srow;               // global seg fetched (de-swizzle)
    const int c0 = w, c1 = w + 4;                     // this wave's chunks

    const bf16* kbase = k  + (size_t)bh * SEQ * HD;
    const bf16* vbase = vt + (size_t)bh * HD * SEQ;
    const float NEG_INF = -__builtin_inff();

    // fragment read pointers (kt-invariant, swizzled): row*64 + ((seg ^ (row&7))<<3)
    const bf16 *kf_p[4][2], *vf_p[4][2], *pf_p[2][2];
#pragma unroll
    for (int nt = 0; nt < 4; nt++) {
        const int r = nt * 16 + l16;
#pragma unroll
        for (int hh = 0; hh < 2; hh++) {
            const int sg = hh * 4 + quad;
            kf_p[nt][hh] = KsF + r * 64 + (((sg ^ (r & 7))) << 3);
            vf_p[nt][hh] = VsF + r * 64 + (((sg ^ (r & 7))) << 3);
        }
    }
#pragma unroll
    for (int mt = 0; mt < 2; mt++) {
        const int r = mt * 16 + l16;
#pragma unroll
        for (int hh = 0; hh < 2; hh++) {
            const int sg = hh * 4 + quad;
            pf_p[mt][hh] = PsF + w * 2048 + r * 64 + (((sg ^ (r & 7))) << 3);
        }
    }

    // Q fragments: 2 m-tiles, A-layout
    bf16x8 qf[2][2];
#pragma unroll
    for (int mt = 0; mt < 2; mt++) {
        const bf16* qrow = q + ((size_t)bh * SEQ + qb * 128 + w * 32 + mt * 16 + l16) * HD;
        qf[mt][0] = *(const bf16x8*)(qrow + quad * 8);
        qf[mt][1] = *(const bf16x8*)(qrow + 32 + quad * 8);
    }

    f32x4 zero = {0.f, 0.f, 0.f, 0.f};
    f32x4 minus10 = {-10.f, -10.f, -10.f, -10.f};
    f32x4 acc_o[2][4];
    float l_acc[2][4];
#pragma unroll
    for (int mt = 0; mt < 2; mt++)
#pragma unroll
        for (int nt = 0; nt < 4; nt++) acc_o[mt][nt] = zero;
#pragma unroll
    for (int mt = 0; mt < 2; mt++)
#pragma unroll
        for (int rg = 0; rg < 4; rg++) l_acc[mt][rg] = 0.f;

    // staging source pointers (advance per kt)
    const bf16* kg0 = kbase + (size_t)(c0 * 8 + srow) * HD + gseg * 8;
    const bf16* kg1 = kbase + (size_t)(c1 * 8 + srow) * HD + gseg * 8;
    const bf16* vg0 = vbase + (size_t)(c0 * 8 + srow) * SEQ + gseg * 8;
    const bf16* vg1 = vbase + (size_t)(c1 * 8 + srow) * SEQ + gseg * 8;
    const int ktmax = 2 * qb + 1;

    for (int kt = 0; kt <= ktmax; kt++) {
        __syncthreads();                    // waves done reading previous tile
        GLL16(kg0, KsF + c0 * 512);
        GLL16(kg1, KsF + c1 * 512);
        GLL16(vg0, VsF + c0 * 512);
        GLL16(vg1, VsF + c1 * 512);
        kg0 += 64 * HD; kg1 += 64 * HD; vg0 += 64; vg1 += 64;
        __syncthreads();                    // vmcnt drain: tile landed

        const int d = qb * 128 + w * 32 - kt * 64;   // wave-row offset vs kv base
        if (d > -32) {                      // else fully masked: skip (wave-uniform)
            // ---- S = Q K^T - 10
            f32x4 accs[2][4];
#pragma unroll
            for (int nt = 0; nt < 4; nt++) {
                const bf16x8 kf0 = *(const bf16x8*)kf_p[nt][0];
                const bf16x8 kf1 = *(const bf16x8*)kf_p[nt][1];
#pragma unroll
                for (int mt = 0; mt < 2; mt++) {
                    f32x4 a = minus10;
                    a = MFMA16(qf[mt][0], kf0, a);
                    a = MFMA16(qf[mt][1], kf1, a);
                    accs[mt][nt] = a;
                }
            }
            // ---- causal mask (only when the 64-kv tile straddles this wave's rows)
            if (d < 64) {
#pragma unroll
                for (int mt = 0; mt < 2; mt++) {
                    const int qr = d + mt * 16 + quad * 4;
#pragma unroll
                    for (int nt = 0; nt < 4; nt++) {
                        const int kv = nt * 16 + l16;
#pragma unroll
                        for (int rg = 0; rg < 4; rg++)
                            if (kv > qr + rg) accs[mt][nt][rg] = NEG_INF;
                    }
                }
            }
            // ---- p = exp(S-10); per-lane row-sum; P -> swizzled wave-private LDS
#pragma unroll
            for (int mt = 0; mt < 2; mt++) {
#pragma unroll
                for (int nt = 0; nt < 4; nt++) {
#pragma unroll
                    for (int rg = 0; rg < 4; rg++) {
                        const float p = __expf(accs[mt][nt][rg]);
                        l_acc[mt][rg] += p;
                        const int prow = mt * 16 + quad * 4 + rg;
                        const int psg  = (nt * 2 + (l16 >> 3)) ^ (prow & 7);
                        PsF[w * 2048 + prow * 64 + psg * 8 + (l16 & 7)] = (bf16)p;
                    }
                }
            }
            // ---- O += P V (in-order DS pipe: no barrier for wave-private P)
            bf16x8 pf[2][2];
#pragma unroll
            for (int mt = 0; mt < 2; mt++) {
                pf[mt][0] = *(const bf16x8*)pf_p[mt][0];
                pf[mt][1] = *(const bf16x8*)pf_p[mt][1];
            }
#pragma unroll
            for (int nt = 0; nt < 4; nt++) {
                const bf16x8 vf0 = *(const bf16x8*)vf_p[nt][0];
                const bf16x8 vf1 = *(const bf16x8*)vf_p[nt][1];
#pragma unroll
                for (int mt = 0; mt < 2; mt++) {
                    acc_o[mt][nt] = MFMA16(pf[mt][0], vf0, acc_o[mt][nt]);
                    acc_o[mt][nt] = MFMA16(pf[mt][1], vf1, acc_o[mt][nt]);
                }
            }
        }
    }

    // ---- epilogue: reduce l over the 16 lanes holding each row, normalize, store
#pragma unroll
    for (int mt = 0; mt < 2; mt++) {
#pragma unroll
        for (int rg = 0; rg < 4; rg++) {
            float rs = l_acc[mt][rg];
            rs += __shfl_xor(rs, 1);
            rs += __shfl_xor(rs, 2);
            rs += __shfl_xor(rs, 4);
            rs += __shfl_xor(rs, 8);
            const float inv = 1.0f / rs;
            const int s = qb * 128 + w * 32 + mt * 16 + quad * 4 + rg;
#pragma unroll
            for (int nt = 0; nt < 4; nt++) {
                const float val = acc_o[mt][nt][rg] * inv;
                y[((size_t)(b * SEQ + s)) * DM + h * HD + nt * 16 + l16] = (bf16)val;
            }
        }
    }
}

// ---------------------------------------------------------------- launch
extern "C" void kernel_launch(void* const* d_in, const int* in_sizes, int n_in,
                              void* d_out, int out_size, void* d_ws, size_t ws_size,
                              hipStream_t stream) {
    const float* x  = (const float*)d_in[0];
    const float* Wq = (const float*)d_in[1];
    const float* bq = (const float*)d_in[2];
    const float* Wk = (const float*)d_in[3];
    const float* bk = (const float*)d_in[4];
    const float* Wv = (const float*)d_in[5];
    const float* bv = (const float*)d_in[6];
    const float* Wo = (const float*)d_in[7];
    const float* bo = (const float*)d_in[8];

    // Workspace layout (88 MB total).
    char* ws = (char*)d_ws;
    bf16* xb   = (bf16*)(ws);                       // 16 MB: x bf16; reused as attn out y
    bf16* wall = (bf16*)(ws + (16ull << 20));       //  8 MB: Wq^T,Wk^T,Wv^T,Wo^T bf16
    bf16* qb   = (bf16*)(ws + (24ull << 20));       // 16 MB
    bf16* kb   = (bf16*)(ws + (40ull << 20));       // 16 MB
    bf16* vb   = (bf16*)(ws + (56ull << 20));       // 16 MB
    bf16* vtb  = (bf16*)(ws + (72ull << 20));       // 16 MB: V^T [B,H,D,S]
    bf16* wot  = wall + 3ull * DM * DM;

    k_prep<<<dim3(16, 16, 5), 256, 0, stream>>>(x, Wq, Wk, Wv, Wo, wall, xb);
    k_gemm<0><<<dim3(64, 8, 3), 256, 0, stream>>>(xb, wall, bq, bk, bv, qb);
    k_vtrans<<<dim3(32, 64), 256, 0, stream>>>(vb, vtb);
    k_attn<<<dim3(64, 16), 256, 0, stream>>>(qb, kb, vtb, xb);
    k_gemm<1><<<dim3(64, 8, 1), 256, 0, stream>>>(xb, wot, bo, bo, bo, d_out);
}

// Round 8
// 255.186 us; speedup vs baseline: 1.4964x; 1.4964x over previous
//
#include <hip/hip_runtime.h>

typedef __bf16 bf16;
typedef __bf16 bf16x2 __attribute__((ext_vector_type(2)));
typedef __bf16 bf16x8 __attribute__((ext_vector_type(8)));
typedef float  f32x4  __attribute__((ext_vector_type(4)));

#define MFMA16(a,b,c) __builtin_amdgcn_mfma_f32_16x16x32_bf16(a,b,c,0,0,0)
// async global->LDS DMA, 16B per lane; LDS dest is wave-uniform base + lane*16
#define GLL16(g, l) __builtin_amdgcn_global_load_lds( \
    (const __attribute__((address_space(1))) unsigned char*)(g), \
    (__attribute__((address_space(3))) unsigned char*)(l), 16, 0, 0)

constexpr int SEQ   = 2048;
constexpr int NH    = 16;
constexpr int HD    = 64;
constexpr int BATCH = 4;
constexpr int DM    = 1024;          // model dim
constexpr int ROWS  = BATCH * SEQ;   // 8192
constexpr size_t TEN = (size_t)BATCH * NH * SEQ * HD;   // 8,388,608 elems per tensor

// ---------------------------------------------------------------- prep: weight transpose (z=0..3) + x convert (z=4)
__global__ __launch_bounds__(256) void k_prep(const float* __restrict__ x,
                                              const float* __restrict__ W0,
                                              const float* __restrict__ W1,
                                              const float* __restrict__ W2,
                                              const float* __restrict__ W3,
                                              bf16* __restrict__ Wt_all,
                                              bf16* __restrict__ xb) {
    __shared__ float T[64][65];
    const int z = blockIdx.z;
    const int t = threadIdx.x;
    if (z == 4) {
        // convert x (fp32 -> bf16): 256 blocks x 256 threads x 128 elems
        const int bi = blockIdx.y * 16 + blockIdx.x;
#pragma unroll
        for (int c = 0; c < 16; c++) {
            const size_t idx = (size_t)c * 524288 + ((size_t)bi * 256 + t) * 8;
            float4 f0 = *(const float4*)(x + idx);
            float4 f1 = *(const float4*)(x + idx + 4);
            bf16x8 o;
            o[0] = (bf16)f0.x; o[1] = (bf16)f0.y; o[2] = (bf16)f0.z; o[3] = (bf16)f0.w;
            o[4] = (bf16)f1.x; o[5] = (bf16)f1.y; o[6] = (bf16)f1.z; o[7] = (bf16)f1.w;
            *(bf16x8*)(xb + idx) = o;
        }
        return;
    }
    const float* W = (z == 0) ? W0 : (z == 1) ? W1 : (z == 2) ? W2 : W3;
    bf16* Wt = Wt_all + (size_t)z * DM * DM;
    const int kb = blockIdx.x, nb = blockIdx.y;
    const int rl = t >> 2, seg = t & 3;
    const float* src = W + (size_t)(kb * 64 + rl) * DM + nb * 64 + seg * 16;
#pragma unroll
    for (int j4 = 0; j4 < 4; j4++) {
        float4 f = *(const float4*)(src + j4 * 4);
        T[rl][seg * 16 + j4 * 4 + 0] = f.x;
        T[rl][seg * 16 + j4 * 4 + 1] = f.y;
        T[rl][seg * 16 + j4 * 4 + 2] = f.z;
        T[rl][seg * 16 + j4 * 4 + 3] = f.w;
    }
    __syncthreads();
    bf16* dst = Wt + (size_t)(nb * 64 + rl) * DM + kb * 64 + seg * 16;
    bf16x8 o0, o1;
#pragma unroll
    for (int j = 0; j < 8; j++) {
        o0[j] = (bf16)T[seg * 16 + j][rl];
        o1[j] = (bf16)T[seg * 16 + 8 + j][rl];
    }
    *(bf16x8*)dst = o0;
    *(bf16x8*)(dst + 8) = o1;
}

// ---------------------------------------------------------------- GEMM (m97 structure)
// 128x128 tile, BK=32, global_load_lds(16B) staging, XOR-swizzled LDS.
// MODE 0: out bf16 scattered to [B,H,S,D] (+ z*TEN), with RoPE fused for z<2
//         (partner element via shfl_xor(1): col^1 lives in lane l16^1, same regs).
// MODE 1: out fp32 [row][col].
template <int MODE>
__global__ __launch_bounds__(256) void k_gemm(const bf16* __restrict__ A,
                                              const bf16* __restrict__ Wt0,
                                              const float* __restrict__ b0,
                                              const float* __restrict__ b1,
                                              const float* __restrict__ b2,
                                              void* __restrict__ out) {
    __shared__ __align__(1024) bf16 AsF[128 * 32];   // 8 KB, swizzled
    __shared__ __align__(1024) bf16 BsF[128 * 32];   // 8 KB, swizzled
    const int z = blockIdx.z;
    const bf16* Wt = Wt0 + (size_t)z * DM * DM;
    const float* bias = (z == 0) ? b0 : (z == 1) ? b1 : b2;

    const int t = threadIdx.x;
    const int w = t >> 6, lane = t & 63, quad = lane >> 4, l16 = lane & 15;
    const int bm = blockIdx.x * 128, bn = blockIdx.y * 128;   // x = M: A-sharers on one XCD
    const int wm = (w >> 1) * 64, wn = (w & 1) * 64;

    // staging: 8 chunks of 1024B per tile; wave w DMAs chunks w*2, w*2+1
    const int c0 = w * 2, c1 = w * 2 + 1;
    const int sg0 = c0 * 64 + lane, sg1 = c1 * 64 + lane;     // 16B segment idx 0..511
    const int r0 = sg0 >> 2, r1 = sg1 >> 2;                   // tile row 0..127
    const int csg0 = (sg0 & 3) ^ ((r0 >> 1) & 3);             // global segment (de-swizzled)
    const int csg1 = (sg1 & 3) ^ ((r1 >> 1) & 3);
    const bf16* gA0 = A  + (size_t)(bm + r0) * DM + csg0 * 8;
    const bf16* gA1 = A  + (size_t)(bm + r1) * DM + csg1 * 8;
    const bf16* gB0 = Wt + (size_t)(bn + r0) * DM + csg0 * 8;
    const bf16* gB1 = Wt + (size_t)(bn + r1) * DM + csg1 * 8;
    bf16* lA0 = AsF + c0 * 512;  // wave-uniform LDS chunk bases
    bf16* lA1 = AsF + c1 * 512;
    bf16* lB0 = BsF + c0 * 512;
    bf16* lB1 = BsF + c1 * 512;

    // fragment read pointers (loop-invariant; swizzled)
    const bf16* pA[4]; const bf16* pB[4];
#pragma unroll
    for (int mt = 0; mt < 4; mt++) {
        const int r = wm + mt * 16 + l16;
        pA[mt] = AsF + r * 32 + ((quad ^ ((r >> 1) & 3)) << 3);
    }
#pragma unroll
    for (int nt = 0; nt < 4; nt++) {
        const int r = wn + nt * 16 + l16;
        pB[nt] = BsF + r * 32 + ((quad ^ ((r >> 1) & 3)) << 3);
    }

    f32x4 zero = {0.f, 0.f, 0.f, 0.f};
    f32x4 acc[4][4];
#pragma unroll
    for (int mt = 0; mt < 4; mt++)
#pragma unroll
        for (int nt = 0; nt < 4; nt++) acc[mt][nt] = zero;

    for (int k0 = 0; k0 < DM; k0 += 32) {
        __syncthreads();               // waves done reading previous tile
        GLL16(gA0, lA0);
        GLL16(gA1, lA1);
        GLL16(gB0, lB0);
        GLL16(gB1, lB1);
        gA0 += 32; gA1 += 32; gB0 += 32; gB1 += 32;
        __syncthreads();               // vmcnt(0) drain: tile landed

        bf16x8 af[4], bfr[4];
#pragma unroll
        for (int mt = 0; mt < 4; mt++) af[mt]  = *(const bf16x8*)pA[mt];
#pragma unroll
        for (int nt = 0; nt < 4; nt++) bfr[nt] = *(const bf16x8*)pB[nt];
#pragma unroll
        for (int mt = 0; mt < 4; mt++)
#pragma unroll
            for (int nt = 0; nt < 4; nt++)
                acc[mt][nt] = MFMA16(af[mt], bfr[nt], acc[mt][nt]);
    }

    float bv[4], invf[4];
#pragma unroll
    for (int nt = 0; nt < 4; nt++) {
        const int col = bn + wn + nt * 16 + l16;
        bv[nt] = bias[col];
        if (MODE == 0) {
            // rope inv_freq for pair index i = (col%64)/2 : 10000^(-i/32)
            const int i = (col & 63) >> 1;
            invf[nt] = __builtin_exp2f(-0.41524101186092029f * (float)i);
        }
    }
    const int odd = l16 & 1;

#pragma unroll
    for (int mt = 0; mt < 4; mt++) {
#pragma unroll
        for (int nt = 0; nt < 4; nt++) {
            const int col = bn + wn + nt * 16 + l16;
#pragma unroll
            for (int rg = 0; rg < 4; rg++) {
                const int row = bm + wm + mt * 16 + quad * 4 + rg;
                float val = acc[mt][nt][rg] + bv[nt];
                if (MODE == 0) {
                    const int b = row >> 11, s = row & (SEQ - 1);
                    const int h = col >> 6, dd = col & 63;
                    if (z < 2) {   // fused RoPE on q,k (q also pre-scaled by 1/8)
                        const float partner = __shfl_xor(val, 1);
                        float sn, cs;
                        __sincosf((float)s * invf[nt], &sn, &cs);
                        val = odd ? (val * cs + partner * sn)
                                  : (val * cs - partner * sn);
                        if (z == 0) val *= 0.125f;
                    }
                    ((bf16*)out)[(size_t)z * TEN +
                                 (((size_t)(b * NH + h)) * SEQ + s) * HD + dd] = (bf16)val;
                } else {
                    ((float*)out)[(size_t)row * DM + col] = val;
                }
            }
        }
    }
}

// ---------------------------------------------------------------- V transpose: [B,H,S,D] -> [B,H,D,S]
__global__ __launch_bounds__(256) void k_vtrans(const bf16* __restrict__ v, bf16* __restrict__ vt) {
    __shared__ float T[64][65];
    const int t = threadIdx.x;
    const int sb = blockIdx.x, bh = blockIdx.y;
    const int rl = t >> 2, seg = t & 3;
    const bf16* src = v + ((size_t)bh * SEQ + sb * 64 + rl) * HD + seg * 16;
    bf16x8 i0 = *(const bf16x8*)src;
    bf16x8 i1 = *(const bf16x8*)(src + 8);
#pragma unroll
    for (int j = 0; j < 8; j++) {
        T[rl][seg * 16 + j]     = (float)i0[j];
        T[rl][seg * 16 + 8 + j] = (float)i1[j];
    }
    __syncthreads();
    bf16* dst = vt + ((size_t)bh * HD + rl) * SEQ + sb * 64 + seg * 16;
    bf16x8 o0, o1;
#pragma unroll
    for (int j = 0; j < 8; j++) {
        o0[j] = (bf16)T[seg * 16 + j][rl];
        o1[j] = (bf16)T[seg * 16 + 8 + j][rl];
    }
    *(bf16x8*)dst = o0;
    *(bf16x8*)(dst + 8) = o1;
}

// ---------------------------------------------------------------- flash attention (causal)
// grid: (bh=64, 16). qb = 15 - blockIdx.y (heavy-first). One 128-row q-block per block.
// __launch_bounds__(256,2): R7's (256,4) made the allocator target 64 VGPRs -> spilled
// accumulators to scratch (WRITE_SIZE 16->50 MB, 2.7x regression). With (256,2) the
// kernel sits at ~100 VGPRs, no spills; residency (4-5 blocks/CU) comes from actual
// VGPR/LDS limits, giving the barrier-overlap the 1024-block grid was built for.
// Wave w owns rows w*32..w*32+31 (2 m-tiles). K/V/P in unpadded XOR-swizzled LDS
// (seg' = seg ^ (row&7)): fragment b128 reads 2-way = free; staging via global_load_lds.
// Softmax: fixed offset -10 in acc init; row-sum deferred to epilogue; P transpose via
// wave-private swizzled LDS (no barrier). Wave-level skip of fully-masked corner.
__global__ __launch_bounds__(256, 2) void k_attn(const bf16* __restrict__ q,
                                                 const bf16* __restrict__ k,
                                                 const bf16* __restrict__ vt,
                                                 bf16* __restrict__ y) {
    __shared__ __align__(1024) bf16 KsF[64 * 64];      // 8 KB [kv][d] swizzled
    __shared__ __align__(1024) bf16 VsF[64 * 64];      // 8 KB [d][kv] swizzled
    __shared__ __align__(1024) bf16 PsF[4 * 32 * 64];  // 16 KB per-wave P scratch, swizzled
    const int t = threadIdx.x;
    const int w = t >> 6, lane = t & 63, quad = lane >> 4, l16 = lane & 15;
    const int bh = blockIdx.x;                // bh fastest => y-blocks of one bh share an XCD
    const int qb = 15 - (int)blockIdx.y;      // heavy blocks dispatch first
    const int b = bh >> 4, h = bh & 15;

    // staging lane mapping: chunk = 8 rows x 64 elems (1 KB); lane -> (row, stored seg)
    const int srow = lane >> 3;                       // row within chunk
    const int gseg = (lane & 7) ^ srow;               // global seg fetched (de-swizzle)
    const int c0 = w, c1 = w + 4;                     // this wave's chunks

    const bf16* kbase = k  + (size_t)bh * SEQ * HD;
    const bf16* vbase = vt + (size_t)bh * HD * SEQ;
    const float NEG_INF = -__builtin_inff();

    // fragment read pointers (kt-invariant, swizzled): row*64 + ((seg ^ (row&7))<<3)
    const bf16 *kf_p[4][2], *vf_p[4][2], *pf_p[2][2];
#pragma unroll
    for (int nt = 0; nt < 4; nt++) {
        const int r = nt * 16 + l16;
#pragma unroll
        for (int hh = 0; hh < 2; hh++) {
            const int sg = hh * 4 + quad;
            kf_p[nt][hh] = KsF + r * 64 + (((sg ^ (r & 7))) << 3);
            vf_p[nt][hh] = VsF + r * 64 + (((sg ^ (r & 7))) << 3);
        }
    }
#pragma unroll
    for (int mt = 0; mt < 2; mt++) {
        const int r = mt * 16 + l16;
#pragma unroll
        for (int hh = 0; hh < 2; hh++) {
            const int sg = hh * 4 + quad;
            pf_p[mt][hh] = PsF + w * 2048 + r * 64 + (((sg ^ (r & 7))) << 3);
        }
    }

    // Q fragments: 2 m-tiles, A-layout
    bf16x8 qf[2][2];
#pragma unroll
    for (int mt = 0; mt < 2; mt++) {
        const bf16* qrow = q + ((size_t)bh * SEQ + qb * 128 + w * 32 + mt * 16 + l16) * HD;
        qf[mt][0] = *(const bf16x8*)(qrow + quad * 8);
        qf[mt][1] = *(const bf16x8*)(qrow + 32 + quad * 8);
    }

    f32x4 zero = {0.f, 0.f, 0.f, 0.f};
    f32x4 minus10 = {-10.f, -10.f, -10.f, -10.f};
    f32x4 acc_o[2][4];
    float l_acc[2][4];
#pragma unroll
    for (int mt = 0; mt < 2; mt++)
#pragma unroll
        for (int nt = 0; nt < 4; nt++) acc_o[mt][nt] = zero;
#pragma unroll
    for (int mt = 0; mt < 2; mt++)
#pragma unroll
        for (int rg = 0; rg < 4; rg++) l_acc[mt][rg] = 0.f;

    // staging source pointers (advance per kt)
    const bf16* kg0 = kbase + (size_t)(c0 * 8 + srow) * HD + gseg * 8;
    const bf16* kg1 = kbase + (size_t)(c1 * 8 + srow) * HD + gseg * 8;
    const bf16* vg0 = vbase + (size_t)(c0 * 8 + srow) * SEQ + gseg * 8;
    const bf16* vg1 = vbase + (size_t)(c1 * 8 + srow) * SEQ + gseg * 8;
    const int ktmax = 2 * qb + 1;

    for (int kt = 0; kt <= ktmax; kt++) {
        __syncthreads();                    // waves done reading previous tile
        GLL16(kg0, KsF + c0 * 512);
        GLL16(kg1, KsF + c1 * 512);
        GLL16(vg0, VsF + c0 * 512);
        GLL16(vg1, VsF + c1 * 512);
        kg0 += 64 * HD; kg1 += 64 * HD; vg0 += 64; vg1 += 64;
        __syncthreads();                    // vmcnt drain: tile landed

        const int d = qb * 128 + w * 32 - kt * 64;   // wave-row offset vs kv base
        if (d > -32) {                      // else fully masked: skip (wave-uniform)
            // ---- S = Q K^T - 10
            f32x4 accs[2][4];
#pragma unroll
            for (int nt = 0; nt < 4; nt++) {
                const bf16x8 kf0 = *(const bf16x8*)kf_p[nt][0];
                const bf16x8 kf1 = *(const bf16x8*)kf_p[nt][1];
#pragma unroll
                for (int mt = 0; mt < 2; mt++) {
                    f32x4 a = minus10;
                    a = MFMA16(qf[mt][0], kf0, a);
                    a = MFMA16(qf[mt][1], kf1, a);
                    accs[mt][nt] = a;
                }
            }
            // ---- causal mask (only when the 64-kv tile straddles this wave's rows)
            if (d < 64) {
#pragma unroll
                for (int mt = 0; mt < 2; mt++) {
                    const int qr = d + mt * 16 + quad * 4;
#pragma unroll
                    for (int nt = 0; nt < 4; nt++) {
                        const int kv = nt * 16 + l16;
#pragma unroll
                        for (int rg = 0; rg < 4; rg++)
                            if (kv > qr + rg) accs[mt][nt][rg] = NEG_INF;
                    }
                }
            }
            // ---- p = exp(S-10); per-lane row-sum; P -> swizzled wave-private LDS
#pragma unroll
            for (int mt = 0; mt < 2; mt++) {
#pragma unroll
                for (int nt = 0; nt < 4; nt++) {
#pragma unroll
                    for (int rg = 0; rg < 4; rg++) {
                        const float p = __expf(accs[mt][nt][rg]);
                        l_acc[mt][rg] += p;
                        const int prow = mt * 16 + quad * 4 + rg;
                        const int psg  = (nt * 2 + (l16 >> 3)) ^ (prow & 7);
                        PsF[w * 2048 + prow * 64 + psg * 8 + (l16 & 7)] = (bf16)p;
                    }
                }
            }
            // ---- O += P V (in-order DS pipe: no barrier for wave-private P)
            bf16x8 pf[2][2];
#pragma unroll
            for (int mt = 0; mt < 2; mt++) {
                pf[mt][0] = *(const bf16x8*)pf_p[mt][0];
                pf[mt][1] = *(const bf16x8*)pf_p[mt][1];
            }
#pragma unroll
            for (int nt = 0; nt < 4; nt++) {
                const bf16x8 vf0 = *(const bf16x8*)vf_p[nt][0];
                const bf16x8 vf1 = *(const bf16x8*)vf_p[nt][1];
#pragma unroll
                for (int mt = 0; mt < 2; mt++) {
                    acc_o[mt][nt] = MFMA16(pf[mt][0], vf0, acc_o[mt][nt]);
                    acc_o[mt][nt] = MFMA16(pf[mt][1], vf1, acc_o[mt][nt]);
                }
            }
        }
    }

    // ---- epilogue: reduce l over the 16 lanes holding each row, normalize, store
#pragma unroll
    for (int mt = 0; mt < 2; mt++) {
#pragma unroll
        for (int rg = 0; rg < 4; rg++) {
            float rs = l_acc[mt][rg];
            rs += __shfl_xor(rs, 1);
            rs += __shfl_xor(rs, 2);
            rs += __shfl_xor(rs, 4);
            rs += __shfl_xor(rs, 8);
            const float inv = 1.0f / rs;
            const int s = qb * 128 + w * 32 + mt * 16 + quad * 4 + rg;
#pragma unroll
            for (int nt = 0; nt < 4; nt++) {
                const float val = acc_o[mt][nt][rg] * inv;
                y[((size_t)(b * SEQ + s)) * DM + h * HD + nt * 16 + l16] = (bf16)val;
            }
        }
    }
}

// ---------------------------------------------------------------- launch
extern "C" void kernel_launch(void* const* d_in, const int* in_sizes, int n_in,
                              void* d_out, int out_size, void* d_ws, size_t ws_size,
                              hipStream_t stream) {
    const float* x  = (const float*)d_in[0];
    const float* Wq = (const float*)d_in[1];
    const float* bq = (const float*)d_in[2];
    const float* Wk = (const float*)d_in[3];
    const float* bk = (const float*)d_in[4];
    const float* Wv = (const float*)d_in[5];
    const float* bv = (const float*)d_in[6];
    const float* Wo = (const float*)d_in[7];
    const float* bo = (const float*)d_in[8];

    // Workspace layout (88 MB total).
    char* ws = (char*)d_ws;
    bf16* xb   = (bf16*)(ws);                       // 16 MB: x bf16; reused as attn out y
    bf16* wall = (bf16*)(ws + (16ull << 20));       //  8 MB: Wq^T,Wk^T,Wv^T,Wo^T bf16
    bf16* qb   = (bf16*)(ws + (24ull << 20));       // 16 MB
    bf16* kb   = (bf16*)(ws + (40ull << 20));       // 16 MB
    bf16* vb   = (bf16*)(ws + (56ull << 20));       // 16 MB
    bf16* vtb  = (bf16*)(ws + (72ull << 20));       // 16 MB: V^T [B,H,D,S]
    bf16* wot  = wall + 3ull * DM * DM;

    k_prep<<<dim3(16, 16, 5), 256, 0, stream>>>(x, Wq, Wk, Wv, Wo, wall, xb);
    k_gemm<0><<<dim3(64, 8, 3), 256, 0, stream>>>(xb, wall, bq, bk, bv, qb);
    k_vtrans<<<dim3(32, 64), 256, 0, stream>>>(vb, vtb);
    k_attn<<<dim3(64, 16), 256, 0, stream>>>(qb, kb, vtb, xb);
    k_gemm<1><<<dim3(64, 8, 1), 256, 0, stream>>>(xb, wot, bo, bo, bo, d_out);
}